// Round 5
// baseline (258.481 us; speedup 1.0000x reference)
//
#include <hip/hip_runtime.h>

#define N_NODES 50000
#define N_REL 16
#define N_BASIS 8
#define N_EDGES 800000
#define CAP 64              // bucket capacity; deg ~ Poisson(16), P(>64) ~ 1e-19

#define WREL_BLOCKS 340     // (17*4096 + 17*1024)/256
#define ZERO_BLOCKS 49      // ceil(12504 int4 / 256)
#define XBF_BLOCKS 1563     // ceil(400000 / 256)  (50000*64 / 8 per thread)
#define SC_BLOCKS 3125      // 800000 / 256
#define AGG_BLOCKS 3125     // 50000 / 16 exact -> no pad nodes anywhere

typedef short s8v __attribute__((ext_vector_type(8)));    // 8 bf16 MFMA A/B frag
typedef float f4v __attribute__((ext_vector_type(4)));    // 4 fp32 MFMA C/D frag

__device__ inline unsigned short f2bf(float f) {
    union { float f; unsigned u; } v; v.f = f;
    unsigned r = (v.u + 0x7FFFu + ((v.u >> 16) & 1u)) >> 16;   // RNE
    return (unsigned short)r;
}

// ---- pre-pass: wrel weights || cursor zero || x -> bf16 cast (R3/R4-verified) ----
__global__ __launch_bounds__(256) void k_pre(const float* __restrict__ x,
                                             const float* __restrict__ b1, const float* __restrict__ c1,
                                             const float* __restrict__ s1f,
                                             const float* __restrict__ b2, const float* __restrict__ c2,
                                             const float* __restrict__ s2f,
                                             unsigned short* __restrict__ w1T,
                                             unsigned short* __restrict__ w2T,
                                             unsigned short* __restrict__ xbf,
                                             int* __restrict__ cursor) {
    int bid = blockIdx.x;
    if (bid >= WREL_BLOCKS + ZERO_BLOCKS) {
        int i = (bid - WREL_BLOCKS - ZERO_BLOCKS) * 256 + threadIdx.x;
        if (i < 400000) {
            const float4* xs = (const float4*)x + (size_t)i * 2;
            float4 v0 = xs[0], v1 = xs[1];
            int4 w;
            w.x = (int)(((unsigned)f2bf(v0.y) << 16) | f2bf(v0.x));
            w.y = (int)(((unsigned)f2bf(v0.w) << 16) | f2bf(v0.z));
            w.z = (int)(((unsigned)f2bf(v1.y) << 16) | f2bf(v1.x));
            w.w = (int)(((unsigned)f2bf(v1.w) << 16) | f2bf(v1.z));
            *(int4*)(xbf + (size_t)i * 8) = w;
        }
        return;
    }
    if (bid >= WREL_BLOCKS) {
        int i = (bid - WREL_BLOCKS) * 256 + threadIdx.x;
        if (i < 12504) ((int4*)cursor)[i] = make_int4(0, 0, 0, 0);
        return;
    }
    int idx = bid * 256 + threadIdx.x;
    if (idx < 17 * 4096) {
        int r = idx >> 12, o = (idx >> 6) & 63, k = idx & 63;
        float acc = 0.f;
        if (r < 16) {
            #pragma unroll
            for (int b = 0; b < N_BASIS; b++) acc += c1[r * N_BASIS + b] * b1[b * 4096 + k * 64 + o];
        } else {
            acc = s1f[k * 64 + o];
        }
        w1T[idx] = f2bf(acc);
    } else {
        int idx2 = idx - 17 * 4096;
        if (idx2 < 17 * 1024) {
            int r = idx2 >> 10, o = (idx2 >> 6) & 15, k = idx2 & 63;
            float acc = 0.f;
            if (r < 16) {
                #pragma unroll
                for (int b = 0; b < N_BASIS; b++) acc += c2[r * N_BASIS + b] * b2[b * 1024 + k * 16 + o];
            } else {
                acc = s2f[k * 16 + o];
            }
            w2T[idx2] = f2bf(acc);
        }
    }
}

// ---- bucket scatter (R0-proven body) ----
__global__ __launch_bounds__(256) void k_scatter(const int* __restrict__ ei,
                                                 const int* __restrict__ et,
                                                 int* __restrict__ cursor,
                                                 int* __restrict__ sed) {
    int e = blockIdx.x * 256 + threadIdx.x;
    if (e < N_EDGES) {
        int src = ei[e];
        int dst = ei[N_EDGES + e];
        int t = et[e];
        int pos = atomicAdd(&cursor[dst], 1);
        if (pos < CAP) sed[dst * CAP + pos] = (t << 16) | src;
    }
}

// ---- wave-level counting sort by relation: pure register/ballot ranking + one
//      ds_permute push. No LDS, no atomics, no cross-lane LDS ordering hazards.
//      Returns sorted packed edge for this lane's slot (garbage for slots >= deg). ----
__device__ __forceinline__ int wave_sort16(int e_raw, bool active, int lane) {
    unsigned long long lt = (1ull << lane) - 1ull;
    int r_e = e_raw >> 16;
    int p = lane;                    // inactive lanes keep own slot (>= deg): bijective
    int st = 0;
    #pragma unroll
    for (int r = 0; r < 16; r++) {
        unsigned long long mask = __ballot(active && (r_e == r));
        if (active && (r_e == r)) p = st + __popcll(mask & lt);
        st += __popcll(mask);
    }
    return __builtin_amdgcn_ds_permute(p << 2, e_raw);
}

// ---- wave-per-node walk: lane = dim. Sorted-run accumulate with flush-on-boundary;
//      run length IS the per-relation count (sorted), so inv comes from a LDS LUT.
//      8 independent gather loads in flight per chunk. ----
__device__ __forceinline__ void walk_node(int se, int deg, int lane, int j,
                                          const unsigned short* __restrict__ srcmat,
                                          unsigned short (*agg)[16][72],
                                          const float* ivlut) {
    #pragma unroll
    for (int r = 0; r < 16; r++) agg[r][j][lane] = 0;   // empty relations -> 0

    float a = 0.f;
    int rprev = -1, run = 0;
    for (int k0 = 0; k0 < deg; k0 += 8) {
        int e0, e1, e2, e3, e4, e5, e6, e7;
        float f0, f1, f2, f3, f4, f5, f6, f7;
        #define LOADK(I, EV, FV)                                                   \
            {                                                                      \
                int kk = k0 + I;                                                   \
                EV = __shfl(se, kk < 63 ? kk : 63);                                \
                int sp = (kk < deg) ? (EV & 0xFFFF) : 0;                           \
                unsigned short v = srcmat[(size_t)sp * 64 + lane];                 \
                FV = __int_as_float(((unsigned)v) << 16);                          \
            }
        LOADK(0, e0, f0) LOADK(1, e1, f1) LOADK(2, e2, f2) LOADK(3, e3, f3)
        LOADK(4, e4, f4) LOADK(5, e5, f5) LOADK(6, e6, f6) LOADK(7, e7, f7)
        #undef LOADK
        #define PROCK(I, EV, FV)                                                   \
            if (k0 + I < deg) {                                                    \
                int r = EV >> 16;                                                  \
                if (r != rprev) {                                                  \
                    if (rprev >= 0)                                                \
                        agg[rprev][j][lane] = f2bf(a * ivlut[run]);                \
                    a = 0.f; run = 0; rprev = r;                                   \
                }                                                                  \
                a += FV; run++;                                                    \
            }
        PROCK(0, e0, f0) PROCK(1, e1, f1) PROCK(2, e2, f2) PROCK(3, e3, f3)
        PROCK(4, e4, f4) PROCK(5, e5, f5) PROCK(6, e6, f6) PROCK(7, e7, f7)
        #undef PROCK
    }
    if (rprev >= 0) agg[rprev][j][lane] = f2bf(a * ivlut[run]);
}

// ---- layer 1: wave-per-node gather -> 1 barrier -> MFMA sweep (R3/R4-proven mappings)
//      Sum_r agg_r@W1_r + x@self1, relu -> h (bf16). 1024 thr = 16 waves = 16 nodes. ----
__global__ __launch_bounds__(1024) void k_agg1(const int* __restrict__ cursor,
                                               const int* __restrict__ sed,
                                               const unsigned short* __restrict__ xbf,
                                               const unsigned short* __restrict__ w1T,
                                               unsigned short* __restrict__ h) {
    __shared__ __align__(16) unsigned short agg[16][16][72];   // [rel][node][dim], stride-72 banks
    __shared__ float ivlut[65];

    int tid = threadIdx.x;
    int wv = tid >> 6, lane = tid & 63;
    int nb = blockIdx.x * 16;
    int j = wv, n = nb + j;

    // every wave writes identical LUT values; own-wave writes are in-order before reads
    ivlut[lane] = 1.0f / (float)(lane > 0 ? lane : 1);
    if (lane == 0) ivlut[64] = 1.0f / 64.0f;

    int deg = cursor[n];
    deg = deg < CAP ? deg : CAP;
    int e_raw = sed[n * CAP + lane];         // CAP entries always addressable
    int se = wave_sort16(e_raw, lane < deg, lane);
    walk_node(se, deg, lane, j, xbf, agg, ivlut);
    __syncthreads();

    if (wv >= 4) return;                     // barrier already passed
    int m = lane & 15, q = lane >> 4;
    int nn = nb + m;
    const unsigned short* wpA = w1T + (wv * 16 + m) * 64 + q * 8;   // A[o=wv*16+m][k]
    f4v D = (f4v){0.f, 0.f, 0.f, 0.f};
    #pragma unroll 4
    for (int r = 0; r < 16; r++) {
        s8v A0 = *(const s8v*)(wpA + r * 4096);
        s8v A1 = *(const s8v*)(wpA + r * 4096 + 32);
        s8v B0 = *(const s8v*)&agg[r][m][q * 8];
        s8v B1 = *(const s8v*)&agg[r][m][32 + q * 8];
        D = __builtin_amdgcn_mfma_f32_16x16x32_bf16(A0, B0, D, 0, 0, 0);
        D = __builtin_amdgcn_mfma_f32_16x16x32_bf16(A1, B1, D, 0, 0, 0);
    }
    {   // self term: relation slot 16, B straight from xbf
        s8v A0 = *(const s8v*)(wpA + 16 * 4096);
        s8v A1 = *(const s8v*)(wpA + 16 * 4096 + 32);
        s8v B0 = *(const s8v*)(xbf + (size_t)nn * 64 + q * 8);
        s8v B1 = *(const s8v*)(xbf + (size_t)nn * 64 + 32 + q * 8);
        D = __builtin_amdgcn_mfma_f32_16x16x32_bf16(A0, B0, D, 0, 0, 0);
        D = __builtin_amdgcn_mfma_f32_16x16x32_bf16(A1, B1, D, 0, 0, 0);
    }
    ushort4 o;
    o.x = f2bf(D[0] > 0.f ? D[0] : 0.f);
    o.y = f2bf(D[1] > 0.f ? D[1] : 0.f);
    o.z = f2bf(D[2] > 0.f ? D[2] : 0.f);
    o.w = f2bf(D[3] > 0.f ? D[3] : 0.f);
    *(ushort4*)(h + (size_t)nn * 64 + wv * 16 + q * 4) = o;    // D col=m(node), row=q*4+i(dim)
}

// ---- layer 2: same skeleton on h; MFMA on wave 0 only (out is 16-wide, fp32) ----
__global__ __launch_bounds__(1024) void k_agg2(const int* __restrict__ cursor,
                                               const int* __restrict__ sed,
                                               const unsigned short* __restrict__ h,
                                               const unsigned short* __restrict__ w2T,
                                               float* __restrict__ out) {
    __shared__ __align__(16) unsigned short agg[16][16][72];
    __shared__ float ivlut[65];

    int tid = threadIdx.x;
    int wv = tid >> 6, lane = tid & 63;
    int nb = blockIdx.x * 16;
    int j = wv, n = nb + j;

    ivlut[lane] = 1.0f / (float)(lane > 0 ? lane : 1);
    if (lane == 0) ivlut[64] = 1.0f / 64.0f;

    int deg = cursor[n];
    deg = deg < CAP ? deg : CAP;
    int e_raw = sed[n * CAP + lane];
    int se = wave_sort16(e_raw, lane < deg, lane);
    walk_node(se, deg, lane, j, h, agg, ivlut);
    __syncthreads();

    if (wv != 0) return;
    int m = lane & 15, q = lane >> 4;
    int nn = nb + m;
    const unsigned short* wpA = w2T + m * 64 + q * 8;          // A[o=m][k], 16 rows
    f4v D = (f4v){0.f, 0.f, 0.f, 0.f};
    #pragma unroll 4
    for (int r = 0; r < 16; r++) {
        s8v A0 = *(const s8v*)(wpA + r * 1024);
        s8v A1 = *(const s8v*)(wpA + r * 1024 + 32);
        s8v B0 = *(const s8v*)&agg[r][m][q * 8];
        s8v B1 = *(const s8v*)&agg[r][m][32 + q * 8];
        D = __builtin_amdgcn_mfma_f32_16x16x32_bf16(A0, B0, D, 0, 0, 0);
        D = __builtin_amdgcn_mfma_f32_16x16x32_bf16(A1, B1, D, 0, 0, 0);
    }
    {   // self term on h
        s8v A0 = *(const s8v*)(wpA + 16 * 1024);
        s8v A1 = *(const s8v*)(wpA + 16 * 1024 + 32);
        s8v B0 = *(const s8v*)(h + (size_t)nn * 64 + q * 8);
        s8v B1 = *(const s8v*)(h + (size_t)nn * 64 + 32 + q * 8);
        D = __builtin_amdgcn_mfma_f32_16x16x32_bf16(A0, B0, D, 0, 0, 0);
        D = __builtin_amdgcn_mfma_f32_16x16x32_bf16(A1, B1, D, 0, 0, 0);
    }
    *(float4*)(out + (size_t)nn * 16 + q * 4) = make_float4(D[0], D[1], D[2], D[3]);
}

extern "C" void kernel_launch(void* const* d_in, const int* in_sizes, int n_in,
                              void* d_out, int out_size, void* d_ws, size_t ws_size,
                              hipStream_t stream) {
    const float* x      = (const float*)d_in[0];
    const float* bases1 = (const float*)d_in[1];
    const float* coeffs1= (const float*)d_in[2];
    const float* self1  = (const float*)d_in[3];
    const float* bases2 = (const float*)d_in[4];
    const float* coeffs2= (const float*)d_in[5];
    const float* self2  = (const float*)d_in[6];
    const int*   ei     = (const int*)d_in[7];
    const int*   et     = (const int*)d_in[8];
    float* out = (float*)d_out;

    char* ws = (char*)d_ws;
    int*            cursor = (int*)(ws + 0);                    //    200,064 (50,016 ints, zeroed)
    unsigned short* w1T    = (unsigned short*)(ws + 200064);    //    139,264
    unsigned short* w2T    = (unsigned short*)(ws + 339328);    //     34,816
    int*            sed    = (int*)(ws + 374144);               // 12,800,000 (50000 x 64 x 4B)
    unsigned short* xbf    = (unsigned short*)(ws + 13174144);  //  6,400,000 (50,000 rows x 128B)
    unsigned short* h      = (unsigned short*)(ws + 19574144);  //  6,400,000 -> 25,974,144

    k_pre<<<WREL_BLOCKS + ZERO_BLOCKS + XBF_BLOCKS, 256, 0, stream>>>(
        x, bases1, coeffs1, self1, bases2, coeffs2, self2, w1T, w2T, xbf, cursor);
    k_scatter<<<SC_BLOCKS, 256, 0, stream>>>(ei, et, cursor, sed);
    k_agg1<<<AGG_BLOCKS, 1024, 0, stream>>>(cursor, sed, xbf, w1T, h);
    k_agg2<<<AGG_BLOCKS, 1024, 0, stream>>>(cursor, sed, h, w2T, out);
}